// Round 1
// baseline (296.548 us; speedup 1.0000x reference)
//
#include <hip/hip_runtime.h>
#include <hip/hip_bf16.h>

typedef __attribute__((ext_vector_type(4))) float f32x4;
typedef __attribute__((ext_vector_type(8))) short bf16x8;
typedef __attribute__((ext_vector_type(8))) unsigned short u16x8;

#define NN 8192
#define SK 8
#define KSL (NN / SK)
#define BM 128

__device__ __forceinline__ short f2bf(float f) {
    unsigned int u = __float_as_uint(f);
    u += 0x7fffu + ((u >> 16) & 1u);
    return (short)(u >> 16);
}

__global__ __launch_bounds__(256) void prep_v(const float* __restrict__ La,
        const float* __restrict__ ve, const float* __restrict__ ve2,
        float* __restrict__ V1, float* __restrict__ V2) {
    int i = blockIdx.x * 256 + threadIdx.x;
    float la = La[i];
    V1[i] = powf(la, ve[0]);
    float b = 2.0f * (la - 1e-8f) - 1.0f;
    V2[i] = powf(b * b + 1.0f, ve2[0]);
}

// C[i][j] = sum_k A(i,k) * B(k,j); A(i,k) = TRANS ? U[k][i] : U[i][k]
// B supplied as Bt bf16 [64][NN] (Bt[j][k] = B[k][j]). Output: P[sk][i][j] partials.
template<int TRANS>
__global__ __launch_bounds__(256) void gemm_pass(const float* __restrict__ U,
        const unsigned short* __restrict__ Bt, float* __restrict__ P) {
    int ib = blockIdx.x, sk = blockIdx.y;
    int tid = threadIdx.x;
    int w = tid >> 6, l = tid & 63;
    int lm = l & 15, g = l >> 4;
    int i0 = ib * BM + w * 32;
    int kbase = sk * KSL;

    f32x4 acc[2][4];
#pragma unroll
    for (int a = 0; a < 2; ++a)
#pragma unroll
        for (int b = 0; b < 4; ++b) acc[a][b] = (f32x4)0.f;

    for (int kt = 0; kt < KSL; kt += 32) {
        int k0 = kbase + kt + 8 * g;   // this lane's k-slot base
        bf16x8 afr[2];
#pragma unroll
        for (int mf = 0; mf < 2; ++mf) {
            int m = i0 + mf * 16 + lm;
            float uv[8];
            if (TRANS) {
                const float* p = U + (size_t)k0 * NN + m;
#pragma unroll
                for (int j = 0; j < 8; ++j) uv[j] = p[(size_t)j * NN];
            } else {
                const float* p = U + (size_t)m * NN + k0;
                f32x4 u0 = *(const f32x4*)p;
                f32x4 u1 = *(const f32x4*)(p + 4);
#pragma unroll
                for (int j = 0; j < 4; ++j) { uv[j] = u0[j]; uv[4 + j] = u1[j]; }
            }
#pragma unroll
            for (int j = 0; j < 8; ++j) afr[mf][j] = f2bf(uv[j]);
        }
        bf16x8 bfr[4];
#pragma unroll
        for (int nf = 0; nf < 4; ++nf)
            bfr[nf] = *(const bf16x8*)(Bt + (size_t)(nf * 16 + lm) * NN + k0);
#pragma unroll
        for (int mf = 0; mf < 2; ++mf)
#pragma unroll
            for (int nf = 0; nf < 4; ++nf)
                acc[mf][nf] = __builtin_amdgcn_mfma_f32_16x16x32_bf16(
                    afr[mf], bfr[nf], acc[mf][nf], 0, 0, 0);
    }
    float* Pp = P + (size_t)sk * NN * 64;
#pragma unroll
    for (int mf = 0; mf < 2; ++mf)
#pragma unroll
        for (int nf = 0; nf < 4; ++nf) {
            f32x4 v = acc[mf][nf];
#pragma unroll
            for (int r = 0; r < 4; ++r)
                Pp[(size_t)(i0 + mf * 16 + 4 * g + r) * 64 + nf * 16 + lm] = v[r];
        }
}

// Bt[j][i] = bf16( (V ? V[i] : 1) * sum_sk P[sk][i][j] ), P shape [nsk][NN][64]
__global__ __launch_bounds__(256) void reduce_t(const float* __restrict__ P, int nsk,
        const float* __restrict__ V, unsigned short* __restrict__ Bt) {
    __shared__ float T[64][65];
    int i0 = blockIdx.x * 64;
    int tid = threadIdx.x;
    int il = tid >> 2, jq = (tid & 3) * 16;
    f32x4 s[4];
#pragma unroll
    for (int q = 0; q < 4; ++q) s[q] = (f32x4)0.f;
    for (int k = 0; k < nsk; ++k) {
        const float* p = P + ((size_t)k * NN + i0 + il) * 64 + jq;
#pragma unroll
        for (int q = 0; q < 4; ++q) s[q] += *(const f32x4*)(p + 4 * q);
    }
    float sc = V ? V[i0 + il] : 1.0f;
#pragma unroll
    for (int q = 0; q < 4; ++q)
#pragma unroll
        for (int c = 0; c < 4; ++c)
            T[il][jq + 4 * q + c] = s[q][c] * sc;
    __syncthreads();
    int j = tid >> 2, iq = (tid & 3) * 16;
    u16x8 o0, o1;
#pragma unroll
    for (int c = 0; c < 8; ++c) o0[c] = (unsigned short)f2bf(T[iq + c][j]);
#pragma unroll
    for (int c = 0; c < 8; ++c) o1[c] = (unsigned short)f2bf(T[iq + 8 + c][j]);
    unsigned short* q = Bt + (size_t)j * NN + i0 + iq;
    *(u16x8*)q = o0;
    *(u16x8*)(q + 8) = o1;
}

// Z2 = sum of partials; hidden = Z2 @ Ww^T + Wb; also per-block BN partial sums.
__global__ __launch_bounds__(256) void reduce_linear(const float* __restrict__ P,
        const float* __restrict__ Ww, const float* __restrict__ Wb,
        float* __restrict__ hidden, float* __restrict__ bsum, float* __restrict__ bsq) {
    __shared__ float z[32][65];
    __shared__ float w[64][65];
    __shared__ float hl[32][65];
    int i0 = blockIdx.x * 32;
    int tid = threadIdx.x;
    for (int e = tid * 4; e < 4096; e += 1024) {
        f32x4 v = *(const f32x4*)(Ww + e);
        int h = e >> 6, c = e & 63;
#pragma unroll
        for (int q = 0; q < 4; ++q) w[h][c + q] = v[q];
    }
    int r = tid >> 3, c8 = (tid & 7) * 8;
    f32x4 a0 = (f32x4)0.f, a1 = (f32x4)0.f;
    for (int k = 0; k < SK; ++k) {
        const float* p = P + ((size_t)k * NN + i0 + r) * 64 + c8;
        a0 += *(const f32x4*)p;
        a1 += *(const f32x4*)(p + 4);
    }
#pragma unroll
    for (int q = 0; q < 4; ++q) { z[r][c8 + q] = a0[q]; z[r][c8 + 4 + q] = a1[q]; }
    __syncthreads();
    int h8 = (tid & 7) * 8;
#pragma unroll
    for (int hh = 0; hh < 8; ++hh) {
        int h = h8 + hh;
        float s = Wb[h];
        for (int c = 0; c < 64; ++c) s += z[r][c] * w[h][c];
        hidden[(size_t)(i0 + r) * 64 + h] = s;
        hl[r][h] = s;
    }
    __syncthreads();
    if (tid < 64) {
        float s = 0.f, q2 = 0.f;
#pragma unroll
        for (int rr = 0; rr < 32; ++rr) {
            float v = hl[rr][tid];
            s += v; q2 += v * v;
        }
        bsum[blockIdx.x * 64 + tid] = s;
        bsq[blockIdx.x * 64 + tid] = q2;
    }
}

__global__ __launch_bounds__(64) void bn_stats(const float* __restrict__ bsum,
        const float* __restrict__ bsq, const float* __restrict__ gamma,
        const float* __restrict__ beta, float* __restrict__ bnc) {
    int h = threadIdx.x;
    float s = 0.f, q = 0.f;
    for (int b = 0; b < 256; ++b) { s += bsum[b * 64 + h]; q += bsq[b * 64 + h]; }
    float mean = s / 8192.0f;
    float var = q / 8192.0f - mean * mean;
    float inv = rsqrtf(var + 1e-5f);
    float sc = gamma[h] * inv;
    bnc[h] = sc;
    bnc[64 + h] = beta[h] - mean * sc;
}

__global__ __launch_bounds__(256) void head(const float* __restrict__ hidden,
        const float* __restrict__ bnc, const float* __restrict__ Mw,
        const float* __restrict__ Mb, float* __restrict__ out0) {
    __shared__ float a[32][65];
    __shared__ float w[32][65];
    __shared__ float o[32][33];
    __shared__ float rowm[32];
    int i0 = blockIdx.x * 32;
    int tid = threadIdx.x;
    for (int e = tid * 4; e < 2048; e += 1024) {
        f32x4 v = *(const f32x4*)(Mw + e);
        int oo = e >> 6, c = e & 63;
#pragma unroll
        for (int q = 0; q < 4; ++q) w[oo][c + q] = v[q];
    }
    int r = tid >> 3, h8 = (tid & 7) * 8;
    const float* hp = hidden + (size_t)(i0 + r) * 64 + h8;
#pragma unroll
    for (int q = 0; q < 8; ++q) {
        int h = h8 + q;
        float v = hp[q] * bnc[h] + bnc[64 + h];
        a[r][h] = fmaxf(v, 0.f);
    }
    __syncthreads();
    int o4 = (tid & 7) * 4;
#pragma unroll
    for (int q = 0; q < 4; ++q) {
        int oo = o4 + q;
        float s = Mb[oo];
        for (int c = 0; c < 64; ++c) s += a[r][c] * w[oo][c];
        o[r][oo] = s;
    }
    __syncthreads();
    if (tid < 32) {
        float m = -3.0e38f;
#pragma unroll
        for (int c = 0; c < 32; ++c) m = fmaxf(m, o[tid][c]);
        float se = 0.f;
#pragma unroll
        for (int c = 0; c < 32; ++c) se += expf(o[tid][c] - m);
        rowm[tid] = m + logf(se);
    }
    __syncthreads();
    f32x4 v;
#pragma unroll
    for (int q = 0; q < 4; ++q) v[q] = o[r][o4 + q] - rowm[r];
    *(f32x4*)(out0 + (size_t)(i0 + r) * 32 + o4) = v;
}

extern "C" void kernel_launch(void* const* d_in, const int* in_sizes, int n_in,
                              void* d_out, int out_size, void* d_ws, size_t ws_size,
                              hipStream_t stream) {
    const float* X   = (const float*)d_in[0];
    const float* La  = (const float*)d_in[1];
    const float* U   = (const float*)d_in[2];
    const float* ve  = (const float*)d_in[3];
    const float* ve2 = (const float*)d_in[4];
    const float* Ww  = (const float*)d_in[5];
    const float* Wb  = (const float*)d_in[6];
    const float* gam = (const float*)d_in[7];
    const float* bet = (const float*)d_in[8];
    const float* Mw  = (const float*)d_in[9];
    const float* Mb  = (const float*)d_in[10];
    float* out0 = (float*)d_out;
    float* hidden = (float*)d_out + (size_t)NN * 32;   // output 1 region

    char* ws = (char*)d_ws;
    float* V1   = (float*)ws;                       // 32 KB
    float* V2   = (float*)(ws + 32768);             // 32 KB
    float* bsum = (float*)(ws + 65536);             // 64 KB
    float* bsq  = (float*)(ws + 131072);            // 64 KB
    float* bnc  = (float*)(ws + 196608);            // 512 B
    unsigned short* Bt = (unsigned short*)(ws + 262144);  // 1 MB bf16 [64][8192]
    float* P    = (float*)(ws + 2097152);           // 16 MB partials [SK][8192][64]

    prep_v<<<32, 256, 0, stream>>>(La, ve, ve2, V1, V2);
    // Xt
    reduce_t<<<128, 256, 0, stream>>>(X, 1, nullptr, Bt);
    // T1 = U^T @ X
    gemm_pass<1><<<dim3(64, SK), 256, 0, stream>>>(U, Bt, P);
    // S1t = V1 * T1 (transposed bf16)
    reduce_t<<<128, 256, 0, stream>>>(P, SK, V1, Bt);
    // Z1 = U @ S1
    gemm_pass<0><<<dim3(64, SK), 256, 0, stream>>>(U, Bt, P);
    reduce_t<<<128, 256, 0, stream>>>(P, SK, nullptr, Bt);
    // T2 = U^T @ Z1
    gemm_pass<1><<<dim3(64, SK), 256, 0, stream>>>(U, Bt, P);
    // S2t = V2 * T2
    reduce_t<<<128, 256, 0, stream>>>(P, SK, V2, Bt);
    // Z2 = U @ S2
    gemm_pass<0><<<dim3(64, SK), 256, 0, stream>>>(U, Bt, P);
    // hidden = Z2 @ Ww^T + Wb  (+ BN partial stats)
    reduce_linear<<<256, 256, 0, stream>>>(P, Ww, Wb, hidden, bsum, bsq);
    bn_stats<<<1, 64, 0, stream>>>(bsum, bsq, gam, bet, bnc);
    head<<<256, 256, 0, stream>>>(hidden, bnc, Mw, Mb, out0);
}